// Round 10
// baseline (1516.216 us; speedup 1.0000x reference)
//
#include <hip/hip_runtime.h>
#include <hip/hip_bf16.h>
#include <stdint.h>

#define Bb 32
#define Lx 512
#define Cc 256
#define Tt 4
#define HID 1024
#define RR (Bb*Lx)          // 16384 logical rows (b*L+l)
#define MRf (RR*Tt)         // 65536 interleaved rows (r*4+t), full problem

typedef int i32x4 __attribute__((ext_vector_type(4)));

// ---------------- async global->LDS, 16B per lane
__device__ __forceinline__ void gl16(const void* g, void* l) {
    __builtin_amdgcn_global_load_lds(
        (const __attribute__((address_space(1))) unsigned int*)g,
        (__attribute__((address_space(3))) unsigned int*)l, 16, 0, 0);
}
__device__ __forceinline__ void blockbar() {
    asm volatile("" ::: "memory");
    __builtin_amdgcn_s_barrier();
    asm volatile("" ::: "memory");
}

// stage NSx64 rows x 64B of an operand tile into LDS (256 threads: 4KB/sweep),
// linear dest; source slot pre-swizzled with involution slot^((row>>1)&3) (rule #21).
template<int NS>
__device__ __forceinline__ void stage_op(const int8_t* __restrict__ g, int K_,
                                         int baseRow, int ko, int8_t* ldsb,
                                         int srow, int sl, int tid) {
    #pragma unroll
    for (int s = 0; s < NS; ++s)
        gl16(g + (size_t)(baseRow + s*64 + srow) * K_ + ko + sl*16,
             ldsb + s*4096 + tid*16);
}

// ---------------- weight quantization: w*2^s = i1*2^14 + i2*2^7 + i3 (exact fixed point)
__global__ void zero_f(float* p, int n) {
    if ((int)threadIdx.x < n) p[threadIdx.x] = 0.0f;
}
// y = matrix id: 0 enc (HID*Cc), 1 cell0, 2 cell1 (HID*HID)
__global__ void absmax3(const float* __restrict__ enc_w, const float* __restrict__ cell_w,
                        float* __restrict__ out) {
    const int y = blockIdx.y;
    const int n = (y == 0) ? HID*Cc : HID*HID;
    const float* w = (y == 0) ? enc_w : cell_w + (size_t)(y-1)*HID*HID;
    float v = 0.0f;
    for (int i = blockIdx.x*256 + threadIdx.x; i < n; i += gridDim.x*256)
        v = fmaxf(v, fabsf(w[i]));
    #pragma unroll
    for (int o = 32; o; o >>= 1) v = fmaxf(v, __shfl_down(v, o));
    if ((threadIdx.x & 63) == 0)
        atomicMax((unsigned*)(out + y), __float_as_uint(v));  // positives: bit-max == val-max
}
__global__ void quant3(const float* __restrict__ enc_w, const float* __restrict__ cell_w,
                       const float* __restrict__ amax,
                       int8_t* __restrict__ qEnc, int8_t* __restrict__ qC0,
                       int8_t* __restrict__ qC1, float* __restrict__ invOut) {
    const int y = blockIdx.y;
    const int n = (y == 0) ? HID*Cc : HID*HID;
    const float* w = (y == 0) ? enc_w : cell_w + (size_t)(y-1)*HID*HID;
    int8_t* q = (y == 0) ? qEnc : (y == 1 ? qC0 : qC1);
    float m = fmaxf(amax[y], 1e-20f);
    float e = floorf(log2f(126.0f * 16384.0f / m));
    float sp = exp2f(e);
    if (m * sp > 126.0f * 16384.0f) sp *= 0.5f;     // guard log2 boundary
    if (blockIdx.x == 0 && threadIdx.x == 0) invOut[y] = 1.0f / sp;
    int i = blockIdx.x*256 + threadIdx.x;
    if (i >= n) return;
    float v  = rintf(w[i] * sp);                    // |v| <= 126*2^14, integer-exact in f32
    float i1 = rintf(v * (1.0f/16384.0f));          // |i1| <= 126
    float r1 = v - i1 * 16384.0f;                   // |r1| <= 2^13, exact
    float i2 = rintf(r1 * (1.0f/128.0f));           // |i2| <= 64
    float r2 = r1 - i2 * 128.0f;                    // |r2| <= 64, exact
    q[i]               = (int8_t)i1;
    q[(size_t)n + i]   = (int8_t)i2;
    q[(size_t)2*n + i] = (int8_t)r2;
}

// ---------------- Stage 1: conv(K=3 over L) + BN + LIF -> i8 spikes, rows r*4+t
// vectorized x4 over channels
__global__ void conv_bn_lif(const float* __restrict__ x,
                            const float* __restrict__ cw, const float* __restrict__ cb,
                            const float* __restrict__ g,  const float* __restrict__ be,
                            const float* __restrict__ mu, const float* __restrict__ var,
                            int8_t* __restrict__ spk) {   // [RR*4][Cc]
    int idx = blockIdx.x * blockDim.x + threadIdx.x;      // over B*L*C/4
    if (idx >= Bb*Lx*Cc/4) return;
    int bl = idx / (Cc/4);
    int c4 = (idx % (Cc/4)) * 4;
    int l  = bl % Lx;
    float4 x0 = *(const float4*)(x + (size_t)bl*Cc + c4);
    float4 xm = (l > 0)    ? *(const float4*)(x + (size_t)bl*Cc + c4 - Cc) : float4{0,0,0,0};
    float4 xp = (l < Lx-1) ? *(const float4*)(x + (size_t)bl*Cc + c4 + Cc) : float4{0,0,0,0};
    float v0=0, v1=0, v2=0, v3=0;
    #pragma unroll
    for (int t = 0; t < Tt; ++t) {
        float w0 = cw[t*3+0], w1 = cw[t*3+1], w2 = cw[t*3+2];
        float inv = g[t] / sqrtf(var[t] + 1e-5f);
        float off = (cb[t] - mu[t]) * inv + be[t];
        float y0 = (w0*xm.x + w1*x0.x + w2*xp.x) * inv + off;
        float y1 = (w0*xm.y + w1*x0.y + w2*xp.y) * inv + off;
        float y2 = (w0*xm.z + w1*x0.z + w2*xp.z) * inv + off;
        float y3 = (w0*xm.w + w1*x0.w + w2*xp.w) * inv + off;
        v0 = v0 + (y0 - v0)*0.5f;  v1 = v1 + (y1 - v1)*0.5f;
        v2 = v2 + (y2 - v2)*0.5f;  v3 = v3 + (y3 - v3)*0.5f;
        float s0 = (v0 >= 1.0f) ? 1.0f : 0.0f;  float s1 = (v1 >= 1.0f) ? 1.0f : 0.0f;
        float s2 = (v2 >= 1.0f) ? 1.0f : 0.0f;  float s3 = (v3 >= 1.0f) ? 1.0f : 0.0f;
        uchar4 pk = { (uint8_t)s0, (uint8_t)s1, (uint8_t)s2, (uint8_t)s3 };
        *(uchar4*)(spk + (size_t)(bl*4 + t)*Cc + c4) = pk;
        v0 *= (1.0f - s0);  v1 *= (1.0f - s1);  v2 *= (1.0f - s2);  v3 *= (1.0f - s3);
    }
}

// ---------------- i8 3-pass GEMM + LIF epilogue
// Block tile 256x256, BK=64, 4 waves (2x2), wave tile 128x128, acc[8][8]=256 AGPR.
// __launch_bounds__(256,1): ~360 regs/wave, 1 wave/SIMD -- max frag reuse
// (16 ds_reads serve 64 MFMA/wave/tile; matrix-bound: 1306 vs ~1130 LDS cyc).
// 2 LDS bufs x (A 16KB + B 16KB) = 64 KB; stage kt+1 issued right after tile-kt
// barrier (lands ~1800 cyc before its vmcnt(0)). acc = (a1*128+a2)*128+a3 exact i32.
template<int K, bool FINAL>
__global__ __launch_bounds__(256, 1)
void gemm_lif(const int8_t* __restrict__ A,
              const int8_t* __restrict__ Wq,      // [3 comps][HID][K]
              const float* __restrict__ invs,     // [1] 2^-s
              const float* __restrict__ bias,
              int8_t* __restrict__ spk_out, float* __restrict__ out_mean) {
    constexpr int KT  = K / 64;           // tiles per component pass
    constexpr int NKT = 3 * KT;           // three fixed-point component passes
    __shared__ int8_t lds[2 * 32768];     // 2 bufs x (A 16KB + B 16KB)

    const int tid  = threadIdx.x;
    const int lane = tid & 63;
    const int wid  = tid >> 6;
    const int wm   = wid >> 1;        // 0..1
    const int wn   = wid & 1;         // 0..1
    const int m0   = blockIdx.x * 256;
    const int n0   = blockIdx.y * 256;
    const int fr   = lane & 15;
    const int lq   = lane >> 4;
    const int swq  = (lq ^ ((fr >> 1) & 3)) * 16;   // conflict-free phys byte slot in 64B row
    const int srow = tid >> 2;                      // staging row within sweep (0..63)
    const int sl   = (tid & 3) ^ ((srow >> 1) & 3); // pre-swizzled source slot

    i32x4 acc[8][8] = {};

    // ---- prologue: stage tile 0 (component 0, ko=0) into buf0
    stage_op<4>(A,  K, m0, 0, &lds[0],     srow, sl, tid);
    stage_op<4>(Wq, K, n0, 0, &lds[16384], srow, sl, tid);

    #pragma unroll 1
    for (int kt = 0; kt < NKT; ++kt) {
        if (kt == KT || kt == 2*KT) {     // component boundary: shift accumulated value
            #pragma unroll
            for (int i = 0; i < 8; ++i)
                #pragma unroll
                for (int j = 0; j < 8; ++j)
                    acc[i][j] *= 128;
        }
        asm volatile("s_waitcnt vmcnt(0)" ::: "memory");   // tile kt landed (issued 1 tile ago)
        blockbar();

        const int cb = (kt & 1) * 32768;
        // ---- issue sweeps for tile kt+1 into the other buffer
        if (kt + 1 < NKT) {
            const int t1 = kt + 1;
            const int pb = (t1 & 1) * 32768;
            const int ko = (t1 % KT) * 64;
            const int8_t* Wc = Wq + (size_t)(t1 / KT) * HID * K;
            stage_op<4>(A,  K, m0, ko, &lds[pb],         srow, sl, tid);
            stage_op<4>(Wc, K, n0, ko, &lds[pb + 16384], srow, sl, tid);
        }

        // ---- half-group 1: 8 reads -> 16 MFMA (starts after ~8 reads land)
        i32x4 af[8], bf[8];
        #pragma unroll
        for (int i = 0; i < 4; ++i)
            af[i] = *(const i32x4*)&lds[cb + (wm*128 + i*16 + fr)*64 + swq];
        #pragma unroll
        for (int j = 0; j < 4; ++j)
            bf[j] = *(const i32x4*)&lds[cb + 16384 + (wn*128 + j*16 + fr)*64 + swq];
        __builtin_amdgcn_s_setprio(1);
        #pragma unroll
        for (int i = 0; i < 4; ++i)
            #pragma unroll
            for (int j = 0; j < 4; ++j)
                acc[i][j] = __builtin_amdgcn_mfma_i32_16x16x64_i8(af[i], bf[j], acc[i][j], 0, 0, 0);
        __builtin_amdgcn_s_setprio(0);
        // ---- half-group 2: 8 reads -> remaining 48 MFMA
        #pragma unroll
        for (int i = 4; i < 8; ++i)
            af[i] = *(const i32x4*)&lds[cb + (wm*128 + i*16 + fr)*64 + swq];
        #pragma unroll
        for (int j = 4; j < 8; ++j)
            bf[j] = *(const i32x4*)&lds[cb + 16384 + (wn*128 + j*16 + fr)*64 + swq];
        __builtin_amdgcn_s_setprio(1);
        #pragma unroll
        for (int i = 0; i < 4; ++i)
            #pragma unroll
            for (int j = 4; j < 8; ++j)
                acc[i][j] = __builtin_amdgcn_mfma_i32_16x16x64_i8(af[i], bf[j], acc[i][j], 0, 0, 0);
        #pragma unroll
        for (int i = 4; i < 8; ++i)
            #pragma unroll
            for (int j = 0; j < 8; ++j)
                acc[i][j] = __builtin_amdgcn_mfma_i32_16x16x64_i8(af[i], bf[j], acc[i][j], 0, 0, 0);
        __builtin_amdgcn_s_setprio(0);
    }

    // ---- epilogue: per-lane LIF over 4 acc regs (= 4 timesteps of one row)
    const float inv = invs[0];
    float bs[8];
    #pragma unroll
    for (int j = 0; j < 8; ++j)
        bs[j] = bias[n0 + wn*128 + j*16 + fr];
    const int rowq = lq * 4;
    #pragma unroll
    for (int i = 0; i < 8; ++i) {
        int rowLocal = m0 + wm*128 + i*16 + rowq;   // t=0 row; rows rowLocal..+3 = t 0..3
        int r = rowLocal >> 2;
        #pragma unroll
        for (int j = 0; j < 8; ++j) {
            int n = n0 + wn*128 + j*16 + fr;
            float v = 0.0f, ssum = 0.0f;
            #pragma unroll
            for (int t = 0; t < 4; ++t) {
                float xv = (float)acc[i][j][t] * inv + bs[j];
                v = v + (xv - v) * 0.5f;
                float s = (v >= 1.0f) ? 1.0f : 0.0f;
                if constexpr (FINAL) ssum += s;
                else spk_out[(size_t)(rowLocal + t) * HID + n] = (int8_t)s;
                v = v * (1.0f - s);
            }
            if constexpr (FINAL) out_mean[(size_t)r * HID + n] = ssum * 0.25f;
        }
    }
}

// ---------------- mean over L, two stages: partials over 64-l segments, then reduce
__global__ void mean_partial(const float* __restrict__ out1, float* __restrict__ part) {
    int idx = blockIdx.x * blockDim.x + threadIdx.x;   // over 8*B*HID
    if (idx >= 8*Bb*HID) return;
    int seg = idx >> 15;                                // /(B*HID)
    int bd  = idx & (Bb*HID - 1);
    int b = bd >> 10, d = bd & (HID-1);
    const float* p = out1 + ((size_t)b*Lx + seg*64)*HID + d;
    float s = 0.0f;
    #pragma unroll 4
    for (int l = 0; l < 64; ++l) s += p[(size_t)l*HID];
    part[idx] = s;
}
__global__ void mean_final(const float* __restrict__ part, float* __restrict__ out2) {
    int idx = blockIdx.x * blockDim.x + threadIdx.x;   // B*HID
    if (idx >= Bb*HID) return;
    float s = 0.0f;
    #pragma unroll
    for (int k = 0; k < 8; ++k) s += part[k*Bb*HID + idx];
    out2[idx] = s * (1.0f / Lx);
}

extern "C" void kernel_launch(void* const* d_in, const int* in_sizes, int n_in,
                              void* d_out, int out_size, void* d_ws, size_t ws_size,
                              hipStream_t stream) {
    const float* x      = (const float*)d_in[0];
    const float* cw     = (const float*)d_in[1];
    const float* cb     = (const float*)d_in[2];
    const float* g      = (const float*)d_in[3];
    const float* be     = (const float*)d_in[4];
    const float* mu     = (const float*)d_in[5];
    const float* var    = (const float*)d_in[6];
    const float* enc_w  = (const float*)d_in[7];
    const float* enc_b  = (const float*)d_in[8];
    const float* cell_w = (const float*)d_in[9];
    const float* cell_b = (const float*)d_in[10];

    float* out1 = (float*)d_out;                    // [RR][HID]
    float* out2 = out1 + (size_t)RR * HID;          // [B][HID]

    // ---- ws layout (~135 MB; 144 MB proven available in round 1)
    // X: spk1 (first 16MB) then reused as spkB (64MB). Y: spkA (64MB).
    uint8_t* ws = (uint8_t*)d_ws;
    int8_t* X = (int8_t*)ws;                               // 64 MB
    int8_t* Y = (int8_t*)(ws + (size_t)64*1024*1024);      // 64 MB
    int8_t* qEnc = (int8_t*)(ws + (size_t)128*1024*1024);  // 3*HID*Cc
    int8_t* qC0  = qEnc + (size_t)3*HID*Cc;                // 3*HID*HID
    int8_t* qC1  = qC0  + (size_t)3*HID*HID;               // 3*HID*HID
    float*  amax = (float*)(qC1 + (size_t)3*HID*HID);
    float*  invv = amax + 4;
    float*  part = invv + 4;                               // 8*B*HID = 1 MB

    // ---- weight quantization (exact 21-bit fixed point, per-matrix pow2 scale)
    zero_f<<<1, 4, 0, stream>>>(amax, 3);
    absmax3<<<dim3(64, 3), 256, 0, stream>>>(enc_w, cell_w, amax);
    quant3<<<dim3((HID*HID + 255)/256, 3), 256, 0, stream>>>(enc_w, cell_w, amax,
                                                             qEnc, qC0, qC1, invv);

    // ---- conv + BN + LIF -> spk1 (= X[0:16MB])
    conv_bn_lif<<<(Bb*Lx*Cc/4 + 255)/256, 256, 0, stream>>>(x, cw, cb, g, be, mu, var, X);

    // ---- full-problem trunk, single dispatch per layer (1024 blocks, 4 rounds)
    dim3 grid(MRf/256, HID/256);   // (256, 4)
    gemm_lif<Cc,  false><<<grid, 256, 0, stream>>>(X, qEnc, invv + 0, enc_b,      Y, nullptr);
    gemm_lif<HID, false><<<grid, 256, 0, stream>>>(Y, qC0,  invv + 1, cell_b,     X, nullptr);
    gemm_lif<HID, true ><<<grid, 256, 0, stream>>>(X, qC1,  invv + 2, cell_b+HID, nullptr, out1);

    // ---- means
    mean_partial<<<(8*Bb*HID + 255)/256, 256, 0, stream>>>(out1, part);
    mean_final<<<(Bb*HID + 255)/256, 256, 0, stream>>>(part, out2);
}

// Round 11
// 624.674 us; speedup vs baseline: 2.4272x; 2.4272x over previous
//
#include <hip/hip_runtime.h>
#include <hip/hip_bf16.h>
#include <stdint.h>

#define Bb 32
#define Lx 512
#define Cc 256
#define Tt 4
#define HID 1024
#define RR (Bb*Lx)          // 16384 logical rows (b*L+l)
#define MRf (RR*Tt)         // 65536 interleaved rows (r*4+t), full problem

typedef int i32x4 __attribute__((ext_vector_type(4)));

// ---------------- async global->LDS, 16B per lane
__device__ __forceinline__ void gl16(const void* g, void* l) {
    __builtin_amdgcn_global_load_lds(
        (const __attribute__((address_space(1))) unsigned int*)g,
        (__attribute__((address_space(3))) unsigned int*)l, 16, 0, 0);
}
__device__ __forceinline__ void blockbar() {
    asm volatile("" ::: "memory");
    __builtin_amdgcn_s_barrier();
    asm volatile("" ::: "memory");
}

// stage one 256row x 128B A tile into LDS: 2 k-planes x 2 row-halves x 2 sweeps.
// Linear dest; source slot pre-swizzled with involution slot^((row>>1)&3) (rule #21).
__device__ __forceinline__ void stageA(const int8_t* __restrict__ g, int K_,
                                       int m0, int ko, int8_t* buf,
                                       int srow, int sl, int tid) {
    #pragma unroll
    for (int h = 0; h < 2; ++h)
        #pragma unroll
        for (int p = 0; p < 2; ++p)
            #pragma unroll
            for (int s = 0; s < 2; ++s)
                gl16(g + (size_t)(m0 + h*128 + s*64 + srow) * K_ + ko + p*64 + sl*16,
                     buf + p*16384 + h*8192 + s*4096 + tid*16);
}

// ---------------- weight quantization: w*2^s = i1*2^14 + i2*2^7 + i3 (exact fixed point)
__global__ void zero_f(float* p, int n) {
    if ((int)threadIdx.x < n) p[threadIdx.x] = 0.0f;
}
// y = matrix id: 0 enc (HID*Cc), 1 cell0, 2 cell1 (HID*HID)
__global__ void absmax3(const float* __restrict__ enc_w, const float* __restrict__ cell_w,
                        float* __restrict__ out) {
    const int y = blockIdx.y;
    const int n = (y == 0) ? HID*Cc : HID*HID;
    const float* w = (y == 0) ? enc_w : cell_w + (size_t)(y-1)*HID*HID;
    float v = 0.0f;
    for (int i = blockIdx.x*256 + threadIdx.x; i < n; i += gridDim.x*256)
        v = fmaxf(v, fabsf(w[i]));
    #pragma unroll
    for (int o = 32; o; o >>= 1) v = fmaxf(v, __shfl_down(v, o));
    if ((threadIdx.x & 63) == 0)
        atomicMax((unsigned*)(out + y), __float_as_uint(v));  // positives: bit-max == val-max
}
__global__ void quant3(const float* __restrict__ enc_w, const float* __restrict__ cell_w,
                       const float* __restrict__ amax,
                       int8_t* __restrict__ qEnc, int8_t* __restrict__ qC0,
                       int8_t* __restrict__ qC1, float* __restrict__ invOut) {
    const int y = blockIdx.y;
    const int n = (y == 0) ? HID*Cc : HID*HID;
    const float* w = (y == 0) ? enc_w : cell_w + (size_t)(y-1)*HID*HID;
    int8_t* q = (y == 0) ? qEnc : (y == 1 ? qC0 : qC1);
    float m = fmaxf(amax[y], 1e-20f);
    float e = floorf(log2f(126.0f * 16384.0f / m));
    float sp = exp2f(e);
    if (m * sp > 126.0f * 16384.0f) sp *= 0.5f;     // guard log2 boundary
    if (blockIdx.x == 0 && threadIdx.x == 0) invOut[y] = 1.0f / sp;
    int i = blockIdx.x*256 + threadIdx.x;
    if (i >= n) return;
    float v  = rintf(w[i] * sp);                    // |v| <= 126*2^14, integer-exact in f32
    float i1 = rintf(v * (1.0f/16384.0f));          // |i1| <= 126
    float r1 = v - i1 * 16384.0f;                   // |r1| <= 2^13, exact
    float i2 = rintf(r1 * (1.0f/128.0f));           // |i2| <= 64
    float r2 = r1 - i2 * 128.0f;                    // |r2| <= 64, exact
    q[i]               = (int8_t)i1;
    q[(size_t)n + i]   = (int8_t)i2;
    q[(size_t)2*n + i] = (int8_t)r2;
}

// ---------------- Stage 1: conv(K=3 over L) + BN + LIF -> i8 spikes, rows r*4+t
__global__ void conv_bn_lif(const float* __restrict__ x,
                            const float* __restrict__ cw, const float* __restrict__ cb,
                            const float* __restrict__ g,  const float* __restrict__ be,
                            const float* __restrict__ mu, const float* __restrict__ var,
                            int8_t* __restrict__ spk) {   // [RR*4][Cc]
    int idx = blockIdx.x * blockDim.x + threadIdx.x;      // over B*L*C/4
    if (idx >= Bb*Lx*Cc/4) return;
    int bl = idx / (Cc/4);
    int c4 = (idx % (Cc/4)) * 4;
    int l  = bl % Lx;
    float4 x0 = *(const float4*)(x + (size_t)bl*Cc + c4);
    float4 xm = (l > 0)    ? *(const float4*)(x + (size_t)bl*Cc + c4 - Cc) : float4{0,0,0,0};
    float4 xp = (l < Lx-1) ? *(const float4*)(x + (size_t)bl*Cc + c4 + Cc) : float4{0,0,0,0};
    float v0=0, v1=0, v2=0, v3=0;
    #pragma unroll
    for (int t = 0; t < Tt; ++t) {
        float w0 = cw[t*3+0], w1 = cw[t*3+1], w2 = cw[t*3+2];
        float inv = g[t] / sqrtf(var[t] + 1e-5f);
        float off = (cb[t] - mu[t]) * inv + be[t];
        float y0 = (w0*xm.x + w1*x0.x + w2*xp.x) * inv + off;
        float y1 = (w0*xm.y + w1*x0.y + w2*xp.y) * inv + off;
        float y2 = (w0*xm.z + w1*x0.z + w2*xp.z) * inv + off;
        float y3 = (w0*xm.w + w1*x0.w + w2*xp.w) * inv + off;
        v0 = v0 + (y0 - v0)*0.5f;  v1 = v1 + (y1 - v1)*0.5f;
        v2 = v2 + (y2 - v2)*0.5f;  v3 = v3 + (y3 - v3)*0.5f;
        float s0 = (v0 >= 1.0f) ? 1.0f : 0.0f;  float s1 = (v1 >= 1.0f) ? 1.0f : 0.0f;
        float s2 = (v2 >= 1.0f) ? 1.0f : 0.0f;  float s3 = (v3 >= 1.0f) ? 1.0f : 0.0f;
        uchar4 pk = { (uint8_t)s0, (uint8_t)s1, (uint8_t)s2, (uint8_t)s3 };
        *(uchar4*)(spk + (size_t)(bl*4 + t)*Cc + c4) = pk;
        v0 *= (1.0f - s0);  v1 *= (1.0f - s1);  v2 *= (1.0f - s2);  v3 *= (1.0f - s3);
    }
}

// ---------------- i8 3-pass GEMM + LIF epilogue
// Block tile 256x128, BK=128, 4 waves (2x2), wave tile 128x64 (acc[8][4]=128 AGPR,
// proven no-spill, 2 waves/SIMD). A double-buffered in LDS (2x32KB -> 2 blocks/CU);
// B NEVER in LDS: each wave loads bf[2][4] straight from L2 within the tile body
// (no cross-barrier register arrays). bf loads pinned BEFORE next-tile A-sweeps via
// sched_barrier so counted vmcnt on bf doesn't drain the prefetch.
// acc = (acc1*128 + acc2)*128 + acc3 exact in i32 (|acc| < 2^31).
template<int K, bool FINAL>
__global__ __launch_bounds__(256, 2)
void gemm_lif(const int8_t* __restrict__ A,
              const int8_t* __restrict__ Wq,      // [3 comps][HID][K]
              const float* __restrict__ invs,     // [1] 2^-s
              const float* __restrict__ bias,
              int8_t* __restrict__ spk_out, float* __restrict__ out_mean) {
    constexpr int KT  = K / 128;          // tiles per component pass
    constexpr int NKT = 3 * KT;           // three fixed-point component passes
    __shared__ int8_t lds[2 * 32768];     // 2 bufs x A 32KB

    const int tid  = threadIdx.x;
    const int lane = tid & 63;
    const int wid  = tid >> 6;
    const int wm   = wid >> 1;        // 0..1
    const int wn   = wid & 1;         // 0..1
    // XCD-chunked decode (2048 blocks): xcd = bid&7 owns 32 m-panels x 8 n-panels,
    // n fast within an m-panel (A panel L2-resident, B fully L2-resident).
    const int bid  = blockIdx.x;
    const int idx_ = bid >> 3;
    const int m0   = ((bid & 7) * 32 + (idx_ >> 3)) * 256;
    const int n0   = (idx_ & 7) * 128;
    const int fr   = lane & 15;
    const int lq   = lane >> 4;
    const int swq  = (lq ^ ((fr >> 1) & 3)) * 16;   // conflict-free phys byte slot in 64B row
    const int srow = tid >> 2;                      // staging row within sweep (0..63)
    const int sl   = (tid & 3) ^ ((srow >> 1) & 3); // pre-swizzled source slot

    i32x4 acc[8][4] = {};

    // ---- prologue: stage A tile 0 into buf0
    stageA(A, K, m0, 0, &lds[0], srow, sl, tid);

    #pragma unroll 1
    for (int kt = 0; kt < NKT; ++kt) {
        if (kt == KT || kt == 2*KT) {     // component boundary: shift accumulated value
            #pragma unroll
            for (int i = 0; i < 8; ++i)
                #pragma unroll
                for (int j = 0; j < 4; ++j)
                    acc[i][j] *= 128;
        }
        asm volatile("s_waitcnt vmcnt(0)" ::: "memory");   // A(kt) landed (issued 1 tile ago)
        blockbar();

        const int cb = (kt & 1) * 32768;

        // ---- B fragments for tile kt: direct global->reg (L2-resident weights)
        const int8_t* Wc = Wq + (size_t)(kt / KT) * HID * K + (kt % KT) * 128 + lq*16;
        i32x4 bf0[4], bf1[4];
        #pragma unroll
        for (int j = 0; j < 4; ++j)
            bf0[j] = *(const i32x4*)(Wc + (size_t)(n0 + wn*64 + j*16 + fr) * K);
        #pragma unroll
        for (int j = 0; j < 4; ++j)
            bf1[j] = *(const i32x4*)(Wc + (size_t)(n0 + wn*64 + j*16 + fr) * K + 64);
        __builtin_amdgcn_sched_barrier(0);   // keep bf loads OLDER than the sweeps below

        // ---- issue A sweeps for tile kt+1 into the other buffer
        if (kt + 1 < NKT)
            stageA(A, K, m0, ((kt + 1) % KT) * 128, &lds[(~kt & 1) * 32768], srow, sl, tid);

        // ---- two k-planes: 8 ds_read_b128 + 32 MFMA each (compiler counted waits)
        i32x4 af[8];
        #pragma unroll
        for (int i = 0; i < 8; ++i)
            af[i] = *(const i32x4*)&lds[cb + wm*8192 + (i*16 + fr)*64 + swq];
        __builtin_amdgcn_s_setprio(1);
        #pragma unroll
        for (int i = 0; i < 8; ++i)
            #pragma unroll
            for (int j = 0; j < 4; ++j)
                acc[i][j] = __builtin_amdgcn_mfma_i32_16x16x64_i8(af[i], bf0[j], acc[i][j], 0, 0, 0);
        __builtin_amdgcn_s_setprio(0);
        #pragma unroll
        for (int i = 0; i < 8; ++i)
            af[i] = *(const i32x4*)&lds[cb + 16384 + wm*8192 + (i*16 + fr)*64 + swq];
        __builtin_amdgcn_s_setprio(1);
        #pragma unroll
        for (int i = 0; i < 8; ++i)
            #pragma unroll
            for (int j = 0; j < 4; ++j)
                acc[i][j] = __builtin_amdgcn_mfma_i32_16x16x64_i8(af[i], bf1[j], acc[i][j], 0, 0, 0);
        __builtin_amdgcn_s_setprio(0);
    }

    // ---- epilogue: per-lane LIF over 4 acc regs (= 4 timesteps of one row)
    const float inv = invs[0];
    float bs[4];
    #pragma unroll
    for (int j = 0; j < 4; ++j)
        bs[j] = bias[n0 + wn*64 + j*16 + fr];
    const int rowq = lq * 4;
    #pragma unroll
    for (int i = 0; i < 8; ++i) {
        int rowLocal = m0 + wm*128 + i*16 + rowq;   // t=0 row; rows rowLocal..+3 = t 0..3
        int r = rowLocal >> 2;
        #pragma unroll
        for (int j = 0; j < 4; ++j) {
            int n = n0 + wn*64 + j*16 + fr;
            float v = 0.0f, ssum = 0.0f;
            #pragma unroll
            for (int t = 0; t < 4; ++t) {
                float xv = (float)acc[i][j][t] * inv + bs[j];
                v = v + (xv - v) * 0.5f;
                float s = (v >= 1.0f) ? 1.0f : 0.0f;
                if constexpr (FINAL) ssum += s;
                else spk_out[(size_t)(rowLocal + t) * HID + n] = (int8_t)s;
                v = v * (1.0f - s);
            }
            if constexpr (FINAL) out_mean[(size_t)r * HID + n] = ssum * 0.25f;
        }
    }
}

// ---------------- mean over L, two stages: partials over 64-l segments, then reduce
__global__ void mean_partial(const float* __restrict__ out1, float* __restrict__ part) {
    int idx = blockIdx.x * blockDim.x + threadIdx.x;   // over 8*B*HID
    if (idx >= 8*Bb*HID) return;
    int seg = idx >> 15;                                // /(B*HID)
    int bd  = idx & (Bb*HID - 1);
    int b = bd >> 10, d = bd & (HID-1);
    const float* p = out1 + ((size_t)b*Lx + seg*64)*HID + d;
    float s = 0.0f;
    #pragma unroll 4
    for (int l = 0; l < 64; ++l) s += p[(size_t)l*HID];
    part[idx] = s;
}
__global__ void mean_final(const float* __restrict__ part, float* __restrict__ out2) {
    int idx = blockIdx.x * blockDim.x + threadIdx.x;   // B*HID
    if (idx >= Bb*HID) return;
    float s = 0.0f;
    #pragma unroll
    for (int k = 0; k < 8; ++k) s += part[k*Bb*HID + idx];
    out2[idx] = s * (1.0f / Lx);
}

extern "C" void kernel_launch(void* const* d_in, const int* in_sizes, int n_in,
                              void* d_out, int out_size, void* d_ws, size_t ws_size,
                              hipStream_t stream) {
    const float* x      = (const float*)d_in[0];
    const float* cw     = (const float*)d_in[1];
    const float* cb     = (const float*)d_in[2];
    const float* g      = (const float*)d_in[3];
    const float* be     = (const float*)d_in[4];
    const float* mu     = (const float*)d_in[5];
    const float* var    = (const float*)d_in[6];
    const float* enc_w  = (const float*)d_in[7];
    const float* enc_b  = (const float*)d_in[8];
    const float* cell_w = (const float*)d_in[9];
    const float* cell_b = (const float*)d_in[10];

    float* out1 = (float*)d_out;                    // [RR][HID]
    float* out2 = out1 + (size_t)RR * HID;          // [B][HID]

    // ---- ws layout (~136 MB; 144 MB proven available)
    uint8_t* ws = (uint8_t*)d_ws;
    int8_t* X = (int8_t*)ws;                               // 64 MB (spk1 16MB -> spkB)
    int8_t* Y = (int8_t*)(ws + (size_t)64*1024*1024);      // 64 MB (spkA)
    int8_t* qEnc = (int8_t*)(ws + (size_t)128*1024*1024);  // 3*HID*Cc
    int8_t* qC0  = qEnc + (size_t)3*HID*Cc;                // 3*HID*HID
    int8_t* qC1  = qC0  + (size_t)3*HID*HID;               // 3*HID*HID
    float*  amax = (float*)(qC1 + (size_t)3*HID*HID);
    float*  invv = amax + 4;
    float*  part = invv + 4;                               // 8*B*HID = 1 MB

    // ---- weight quantization (exact 21-bit fixed point, per-matrix pow2 scale)
    zero_f<<<1, 4, 0, stream>>>(amax, 3);
    absmax3<<<dim3(64, 3), 256, 0, stream>>>(enc_w, cell_w, amax);
    quant3<<<dim3((HID*HID + 255)/256, 3), 256, 0, stream>>>(enc_w, cell_w, amax,
                                                             qEnc, qC0, qC1, invv);

    // ---- conv + BN + LIF -> spk1 (= X[0:16MB])
    conv_bn_lif<<<(Bb*Lx*Cc/4 + 255)/256, 256, 0, stream>>>(x, cw, cb, g, be, mu, var, X);

    // ---- full-problem trunk, one dispatch per layer: 2048 blocks (256 m x 8 n)
    gemm_lif<Cc,  false><<<2048, 256, 0, stream>>>(X, qEnc, invv + 0, enc_b,      Y, nullptr);
    gemm_lif<HID, false><<<2048, 256, 0, stream>>>(Y, qC0,  invv + 1, cell_b,     X, nullptr);
    gemm_lif<HID, true ><<<2048, 256, 0, stream>>>(X, qC1,  invv + 2, cell_b+HID, nullptr, out1);

    // ---- means
    mean_partial<<<(8*Bb*HID + 255)/256, 256, 0, stream>>>(out1, part);
    mean_final<<<(Bb*HID + 255)/256, 256, 0, stream>>>(part, out2);
}

// Round 12
// 521.334 us; speedup vs baseline: 2.9083x; 1.1982x over previous
//
#include <hip/hip_runtime.h>
#include <hip/hip_bf16.h>
#include <stdint.h>

#define Bb 32
#define Lx 512
#define Cc 256
#define Tt 4
#define HID 1024
#define RR (Bb*Lx)          // 16384 logical rows (b*L+l)
#define MRf (RR*Tt)         // 65536 interleaved rows (r*4+t)

typedef int i32x4 __attribute__((ext_vector_type(4)));

// ---------------- async global->LDS, 16B per lane
__device__ __forceinline__ void gl16(const void* g, void* l) {
    __builtin_amdgcn_global_load_lds(
        (const __attribute__((address_space(1))) unsigned int*)g,
        (__attribute__((address_space(3))) unsigned int*)l, 16, 0, 0);
}
__device__ __forceinline__ void blockbar() {
    asm volatile("" ::: "memory");
    __builtin_amdgcn_s_barrier();
    asm volatile("" ::: "memory");
}

// one staging sweep (512 threads x 16B = 8KB): rows h*128+(tid>>2) of a 256-row
// operand, k-plane p (64B). Linear LDS dest; source slot pre-swizzled with the
// involution slot^((row>>1)&3) (rule #21).
__device__ __forceinline__ void sweep(const int8_t* __restrict__ g, int K_,
                                      int rowBase, int ko, int h, int p,
                                      int8_t* buf, int srow, int sl, int tid) {
    gl16(g + (size_t)(rowBase + h*128 + srow) * K_ + ko + p*64 + sl*16,
         buf + p*16384 + h*8192 + tid*16);
}

// ---------------- weight quantization: w*2^s = i1*2^14 + i2*2^7 + i3 (exact fixed point)
__global__ void zero_f(float* p, int n) {
    if ((int)threadIdx.x < n) p[threadIdx.x] = 0.0f;
}
__global__ void absmax3(const float* __restrict__ enc_w, const float* __restrict__ cell_w,
                        float* __restrict__ out) {
    const int y = blockIdx.y;
    const int n = (y == 0) ? HID*Cc : HID*HID;
    const float* w = (y == 0) ? enc_w : cell_w + (size_t)(y-1)*HID*HID;
    float v = 0.0f;
    for (int i = blockIdx.x*256 + threadIdx.x; i < n; i += gridDim.x*256)
        v = fmaxf(v, fabsf(w[i]));
    #pragma unroll
    for (int o = 32; o; o >>= 1) v = fmaxf(v, __shfl_down(v, o));
    if ((threadIdx.x & 63) == 0)
        atomicMax((unsigned*)(out + y), __float_as_uint(v));  // positives: bit-max == val-max
}
__global__ void quant3(const float* __restrict__ enc_w, const float* __restrict__ cell_w,
                       const float* __restrict__ amax,
                       int8_t* __restrict__ qEnc, int8_t* __restrict__ qC0,
                       int8_t* __restrict__ qC1, float* __restrict__ invOut) {
    const int y = blockIdx.y;
    const int n = (y == 0) ? HID*Cc : HID*HID;
    const float* w = (y == 0) ? enc_w : cell_w + (size_t)(y-1)*HID*HID;
    int8_t* q = (y == 0) ? qEnc : (y == 1 ? qC0 : qC1);
    float m = fmaxf(amax[y], 1e-20f);
    float e = floorf(log2f(126.0f * 16384.0f / m));
    float sp = exp2f(e);
    if (m * sp > 126.0f * 16384.0f) sp *= 0.5f;     // guard log2 boundary
    if (blockIdx.x == 0 && threadIdx.x == 0) invOut[y] = 1.0f / sp;
    int i = blockIdx.x*256 + threadIdx.x;
    if (i >= n) return;
    float v  = rintf(w[i] * sp);                    // |v| <= 126*2^14, integer-exact in f32
    float i1 = rintf(v * (1.0f/16384.0f));          // |i1| <= 126
    float r1 = v - i1 * 16384.0f;                   // |r1| <= 2^13, exact
    float i2 = rintf(r1 * (1.0f/128.0f));           // |i2| <= 64
    float r2 = r1 - i2 * 128.0f;                    // |r2| <= 64, exact
    q[i]               = (int8_t)i1;
    q[(size_t)n + i]   = (int8_t)i2;
    q[(size_t)2*n + i] = (int8_t)r2;
}

// ---------------- Stage 1: conv(K=3 over L) + BN + LIF -> i8 spikes, rows r*4+t
__global__ void conv_bn_lif(const float* __restrict__ x,
                            const float* __restrict__ cw, const float* __restrict__ cb,
                            const float* __restrict__ g,  const float* __restrict__ be,
                            const float* __restrict__ mu, const float* __restrict__ var,
                            int8_t* __restrict__ spk) {   // [RR*4][Cc]
    int idx = blockIdx.x * blockDim.x + threadIdx.x;      // over B*L*C/4
    if (idx >= Bb*Lx*Cc/4) return;
    int bl = idx / (Cc/4);
    int c4 = (idx % (Cc/4)) * 4;
    int l  = bl % Lx;
    float4 x0 = *(const float4*)(x + (size_t)bl*Cc + c4);
    float4 xm = (l > 0)    ? *(const float4*)(x + (size_t)bl*Cc + c4 - Cc) : float4{0,0,0,0};
    float4 xp = (l < Lx-1) ? *(const float4*)(x + (size_t)bl*Cc + c4 + Cc) : float4{0,0,0,0};
    float v0=0, v1=0, v2=0, v3=0;
    #pragma unroll
    for (int t = 0; t < Tt; ++t) {
        float w0 = cw[t*3+0], w1 = cw[t*3+1], w2 = cw[t*3+2];
        float inv = g[t] / sqrtf(var[t] + 1e-5f);
        float off = (cb[t] - mu[t]) * inv + be[t];
        float y0 = (w0*xm.x + w1*x0.x + w2*xp.x) * inv + off;
        float y1 = (w0*xm.y + w1*x0.y + w2*xp.y) * inv + off;
        float y2 = (w0*xm.z + w1*x0.z + w2*xp.z) * inv + off;
        float y3 = (w0*xm.w + w1*x0.w + w2*xp.w) * inv + off;
        v0 = v0 + (y0 - v0)*0.5f;  v1 = v1 + (y1 - v1)*0.5f;
        v2 = v2 + (y2 - v2)*0.5f;  v3 = v3 + (y3 - v3)*0.5f;
        float s0 = (v0 >= 1.0f) ? 1.0f : 0.0f;  float s1 = (v1 >= 1.0f) ? 1.0f : 0.0f;
        float s2 = (v2 >= 1.0f) ? 1.0f : 0.0f;  float s3 = (v3 >= 1.0f) ? 1.0f : 0.0f;
        uchar4 pk = { (uint8_t)s0, (uint8_t)s1, (uint8_t)s2, (uint8_t)s3 };
        *(uchar4*)(spk + (size_t)(bl*4 + t)*Cc + c4) = pk;
        v0 *= (1.0f - s0);  v1 *= (1.0f - s1);  v2 *= (1.0f - s2);  v3 *= (1.0f - s3);
    }
}

// ---------------- i8 3-pass GEMM, m201 4-phase discipline + LIF epilogue
// Tile 256x256, BK=128 (2 k-planes), 8 waves (2M x 4N), wave tile 128x64
// (acc[8][4]=128 AGPR, proven no-spill). 2 LDS bufs x 64KB = 128KB.
// Per tile: vmcnt(0)+bar at top (sweeps issued 4 phases early -> free), then
// 4 phases {ds_reads, 2 sweeps, bar, lgkm0, sched_bar, prio1, 16 MFMA, prio0, bar}
// partitioned (k-plane x m-half): every phase's 16 MFMAs hit DISTINCT acc ->
// barriers never drain the matrix pipe (m201's key property).
// acc = (acc1*128 + acc2)*128 + acc3 exact in i32 (|acc| < 2^31).
template<int K, bool FINAL>
__global__ __launch_bounds__(512, 2)
void gemm_lif(const int8_t* __restrict__ A,
              const int8_t* __restrict__ Wq,      // [3 comps][HID][K]
              const float* __restrict__ invs,     // [1] 2^-s
              const float* __restrict__ bias,
              int8_t* __restrict__ spk_out, float* __restrict__ out_mean) {
    constexpr int KT  = K / 128;          // tiles per component pass
    constexpr int NKT = 3 * KT;           // three fixed-point component passes
    __shared__ int8_t lds[2 * 65536];     // 2 bufs x (A 32KB + B 32KB)

    const int tid  = threadIdx.x;
    const int lane = tid & 63;
    const int wid  = tid >> 6;
    const int wm   = wid >> 2;        // 0..1
    const int wn   = wid & 3;         // 0..3
    const int m0   = blockIdx.x * 256;
    const int n0   = blockIdx.y * 256;
    const int fr   = lane & 15;
    const int lq   = lane >> 4;
    const int swq  = (lq ^ ((fr >> 1) & 3)) * 16;   // conflict-free phys byte slot in 64B row
    const int srow = tid >> 2;                      // staging row (0..127)
    const int sl   = (tid & 3) ^ ((srow >> 1) & 3); // pre-swizzled source slot

    i32x4 acc[8][4] = {};
    i32x4 af[4], bf[4];

    // ---- prologue: stage tile 0 (component 0, ko=0) into buf0
    #pragma unroll
    for (int h = 0; h < 2; ++h)
        #pragma unroll
        for (int p = 0; p < 2; ++p) {
            sweep(A,  K, m0, 0, h, p, &lds[0],     srow, sl, tid);
            sweep(Wq, K, n0, 0, h, p, &lds[32768], srow, sl, tid);
        }

    #pragma unroll 1
    for (int kt = 0; kt < NKT; ++kt) {
        if (kt == KT || kt == 2*KT) {     // component boundary: shift accumulated value
            #pragma unroll
            for (int i = 0; i < 8; ++i)
                #pragma unroll
                for (int j = 0; j < 4; ++j)
                    acc[i][j] *= 128;
        }
        asm volatile("s_waitcnt vmcnt(0)" ::: "memory");   // tile kt landed (issued 1 tile ago)
        blockbar();

        const int cb = (kt & 1) * 65536;
        const int t1 = kt + 1;
        const bool pre = (t1 < NKT);
        const int pb = (t1 & 1) * 65536;
        const int ko = (t1 % KT) * 128;
        const int8_t* Wc = Wq + (size_t)(t1 / KT) * HID * K;

        #pragma unroll
        for (int ph = 0; ph < 4; ++ph) {
            const int kp = ph >> 1;           // k-plane of this phase's MFMAs
            const int mh = ph & 1;            // m-half
            // ---- ds_reads for THIS phase (complete during the barrier + lgkm0)
            #pragma unroll
            for (int i = 0; i < 4; ++i)
                af[i] = *(const i32x4*)&lds[cb + kp*16384
                          + (wm*128 + (mh*4 + i)*16 + fr)*64 + swq];
            if (mh == 0) {                    // bf[kp] loaded once per k-plane, live 2 phases
                #pragma unroll
                for (int j = 0; j < 4; ++j)
                    bf[j] = *(const i32x4*)&lds[cb + 32768 + kp*16384
                              + (wn*64 + j*16 + fr)*64 + swq];
            }
            // ---- 2 staging sweeps for tile kt+1 (phases 0,1: A; 2,3: B)
            if (pre) {
                if (ph < 2) {
                    sweep(A,  K, m0, ko, 0, ph, &lds[pb],         srow, sl, tid);
                    sweep(A,  K, m0, ko, 1, ph, &lds[pb],         srow, sl, tid);
                } else {
                    sweep(Wc, K, n0, ko, 0, ph-2, &lds[pb + 32768], srow, sl, tid);
                    sweep(Wc, K, n0, ko, 1, ph-2, &lds[pb + 32768], srow, sl, tid);
                }
            }
            blockbar();
            asm volatile("s_waitcnt lgkmcnt(0)" ::: "memory");
            __builtin_amdgcn_sched_barrier(0);
            __builtin_amdgcn_s_setprio(1);
            #pragma unroll
            for (int i = 0; i < 4; ++i)
                #pragma unroll
                for (int j = 0; j < 4; ++j)
                    acc[mh*4 + i][j] = __builtin_amdgcn_mfma_i32_16x16x64_i8(
                        af[i], bf[j], acc[mh*4 + i][j], 0, 0, 0);
            __builtin_amdgcn_s_setprio(0);
            blockbar();
        }
    }

    // ---- epilogue: per-lane LIF over 4 acc regs (= 4 timesteps of one row)
    const float inv = invs[0];
    float bs[4];
    #pragma unroll
    for (int j = 0; j < 4; ++j)
        bs[j] = bias[n0 + wn*64 + j*16 + fr];
    const int rowq = lq * 4;
    #pragma unroll
    for (int i = 0; i < 8; ++i) {
        int rowLocal = m0 + wm*128 + i*16 + rowq;   // t=0 row; rows rowLocal..+3 = t 0..3
        int r = rowLocal >> 2;
        #pragma unroll
        for (int j = 0; j < 4; ++j) {
            int n = n0 + wn*64 + j*16 + fr;
            float v = 0.0f, ssum = 0.0f;
            #pragma unroll
            for (int t = 0; t < 4; ++t) {
                float xv = (float)acc[i][j][t] * inv + bs[j];
                v = v + (xv - v) * 0.5f;
                float s = (v >= 1.0f) ? 1.0f : 0.0f;
                if constexpr (FINAL) ssum += s;
                else spk_out[(size_t)(rowLocal + t) * HID + n] = (int8_t)s;
                v = v * (1.0f - s);
            }
            if constexpr (FINAL) out_mean[(size_t)r * HID + n] = ssum * 0.25f;
        }
    }
}

// ---------------- mean over L, two stages
__global__ void mean_partial(const float* __restrict__ out1, float* __restrict__ part) {
    int idx = blockIdx.x * blockDim.x + threadIdx.x;   // over 8*B*HID
    if (idx >= 8*Bb*HID) return;
    int seg = idx >> 15;
    int bd  = idx & (Bb*HID - 1);
    int b = bd >> 10, d = bd & (HID-1);
    const float* p = out1 + ((size_t)b*Lx + seg*64)*HID + d;
    float s = 0.0f;
    #pragma unroll 4
    for (int l = 0; l < 64; ++l) s += p[(size_t)l*HID];
    part[idx] = s;
}
__global__ void mean_final(const float* __restrict__ part, float* __restrict__ out2) {
    int idx = blockIdx.x * blockDim.x + threadIdx.x;   // B*HID
    if (idx >= Bb*HID) return;
    float s = 0.0f;
    #pragma unroll
    for (int k = 0; k < 8; ++k) s += part[k*Bb*HID + idx];
    out2[idx] = s * (1.0f / Lx);
}

extern "C" void kernel_launch(void* const* d_in, const int* in_sizes, int n_in,
                              void* d_out, int out_size, void* d_ws, size_t ws_size,
                              hipStream_t stream) {
    const float* x      = (const float*)d_in[0];
    const float* cw     = (const float*)d_in[1];
    const float* cb     = (const float*)d_in[2];
    const float* g      = (const float*)d_in[3];
    const float* be     = (const float*)d_in[4];
    const float* mu     = (const float*)d_in[5];
    const float* var    = (const float*)d_in[6];
    const float* enc_w  = (const float*)d_in[7];
    const float* enc_b  = (const float*)d_in[8];
    const float* cell_w = (const float*)d_in[9];
    const float* cell_b = (const float*)d_in[10];

    float* out1 = (float*)d_out;                    // [RR][HID]
    float* out2 = out1 + (size_t)RR * HID;          // [B][HID]

    // ---- ws layout (~136 MB; 144 MB proven available)
    uint8_t* ws = (uint8_t*)d_ws;
    int8_t* X = (int8_t*)ws;                               // 64 MB (spk1 16MB -> layer2 out)
    int8_t* Y = (int8_t*)(ws + (size_t)64*1024*1024);      // 64 MB (layer1 out)
    int8_t* qEnc = (int8_t*)(ws + (size_t)128*1024*1024);  // 3*HID*Cc
    int8_t* qC0  = qEnc + (size_t)3*HID*Cc;                // 3*HID*HID
    int8_t* qC1  = qC0  + (size_t)3*HID*HID;               // 3*HID*HID
    float*  amax = (float*)(qC1 + (size_t)3*HID*HID);
    float*  invv = amax + 4;
    float*  part = invv + 4;                               // 8*B*HID = 1 MB

    // ---- weight quantization (exact 21-bit fixed point, per-matrix pow2 scale)
    zero_f<<<1, 4, 0, stream>>>(amax, 3);
    absmax3<<<dim3(64, 3), 256, 0, stream>>>(enc_w, cell_w, amax);
    quant3<<<dim3((HID*HID + 255)/256, 3), 256, 0, stream>>>(enc_w, cell_w, amax,
                                                             qEnc, qC0, qC1, invv);

    // ---- conv + BN + LIF -> spk1 (= X[0:16MB])
    conv_bn_lif<<<(Bb*Lx*Cc/4 + 255)/256, 256, 0, stream>>>(x, cw, cb, g, be, mu, var, X);

    // ---- full-problem trunk, one dispatch per layer (256 x 4 = 1024 blocks)
    dim3 grid(MRf/256, HID/256);
    gemm_lif<Cc,  false><<<grid, 512, 0, stream>>>(X, qEnc, invv + 0, enc_b,      Y, nullptr);
    gemm_lif<HID, false><<<grid, 512, 0, stream>>>(Y, qC0,  invv + 1, cell_b,     X, nullptr);
    gemm_lif<HID, true ><<<grid, 512, 0, stream>>>(X, qC1,  invv + 2, cell_b+HID, nullptr, out1);

    // ---- means
    mean_partial<<<(8*Bb*HID + 255)/256, 256, 0, stream>>>(out1, part);
    mean_final<<<(Bb*HID + 255)/256, 256, 0, stream>>>(part, out2);
}

// Round 13
// 448.983 us; speedup vs baseline: 3.3770x; 1.1611x over previous
//
#include <hip/hip_runtime.h>
#include <hip/hip_bf16.h>
#include <stdint.h>

#define Bb 32
#define Lx 512
#define Cc 256
#define Tt 4
#define HID 1024
#define RR (Bb*Lx)          // 16384 logical rows (b*L+l)
#define MRf (RR*Tt)         // 65536 interleaved rows (r*4+t)

typedef int i32x4 __attribute__((ext_vector_type(4)));

// ---------------- async global->LDS, 16B per lane
__device__ __forceinline__ void gl16(const void* g, void* l) {
    __builtin_amdgcn_global_load_lds(
        (const __attribute__((address_space(1))) unsigned int*)g,
        (__attribute__((address_space(3))) unsigned int*)l, 16, 0, 0);
}
__device__ __forceinline__ void blockbar() {
    asm volatile("" ::: "memory");
    __builtin_amdgcn_s_barrier();
    asm volatile("" ::: "memory");
}

// ---------------- weight quantization: w*2^s = i1*2^14 + i2*2^7 + i3 (exact fixed point)
__global__ void zero_f(float* p, int n) {
    if ((int)threadIdx.x < n) p[threadIdx.x] = 0.0f;
}
__global__ void absmax3(const float* __restrict__ enc_w, const float* __restrict__ cell_w,
                        float* __restrict__ out) {
    const int y = blockIdx.y;
    const int n = (y == 0) ? HID*Cc : HID*HID;
    const float* w = (y == 0) ? enc_w : cell_w + (size_t)(y-1)*HID*HID;
    float v = 0.0f;
    for (int i = blockIdx.x*256 + threadIdx.x; i < n; i += gridDim.x*256)
        v = fmaxf(v, fabsf(w[i]));
    #pragma unroll
    for (int o = 32; o; o >>= 1) v = fmaxf(v, __shfl_down(v, o));
    if ((threadIdx.x & 63) == 0)
        atomicMax((unsigned*)(out + y), __float_as_uint(v));  // positives: bit-max == val-max
}
__global__ void quant3(const float* __restrict__ enc_w, const float* __restrict__ cell_w,
                       const float* __restrict__ amax,
                       int8_t* __restrict__ qEnc, int8_t* __restrict__ qC0,
                       int8_t* __restrict__ qC1, float* __restrict__ invOut) {
    const int y = blockIdx.y;
    const int n = (y == 0) ? HID*Cc : HID*HID;
    const float* w = (y == 0) ? enc_w : cell_w + (size_t)(y-1)*HID*HID;
    int8_t* q = (y == 0) ? qEnc : (y == 1 ? qC0 : qC1);
    float m = fmaxf(amax[y], 1e-20f);
    float e = floorf(log2f(126.0f * 16384.0f / m));
    float sp = exp2f(e);
    if (m * sp > 126.0f * 16384.0f) sp *= 0.5f;     // guard log2 boundary
    if (blockIdx.x == 0 && threadIdx.x == 0) invOut[y] = 1.0f / sp;
    int i = blockIdx.x*256 + threadIdx.x;
    if (i >= n) return;
    float v  = rintf(w[i] * sp);                    // |v| <= 126*2^14, integer-exact in f32
    float i1 = rintf(v * (1.0f/16384.0f));          // |i1| <= 126
    float r1 = v - i1 * 16384.0f;                   // |r1| <= 2^13, exact
    float i2 = rintf(r1 * (1.0f/128.0f));           // |i2| <= 64
    float r2 = r1 - i2 * 128.0f;                    // |r2| <= 64, exact
    q[i]               = (int8_t)i1;
    q[(size_t)n + i]   = (int8_t)i2;
    q[(size_t)2*n + i] = (int8_t)r2;
}

// ---------------- Stage 1: conv(K=3 over L) + BN + LIF -> i8 spikes, rows r*4+t
__global__ void conv_bn_lif(const float* __restrict__ x,
                            const float* __restrict__ cw, const float* __restrict__ cb,
                            const float* __restrict__ g,  const float* __restrict__ be,
                            const float* __restrict__ mu, const float* __restrict__ var,
                            int8_t* __restrict__ spk) {   // [RR*4][Cc]
    int idx = blockIdx.x * blockDim.x + threadIdx.x;      // over B*L*C/4
    if (idx >= Bb*Lx*Cc/4) return;
    int bl = idx / (Cc/4);
    int c4 = (idx % (Cc/4)) * 4;
    int l  = bl % Lx;
    float4 x0 = *(const float4*)(x + (size_t)bl*Cc + c4);
    float4 xm = (l > 0)    ? *(const float4*)(x + (size_t)bl*Cc + c4 - Cc) : float4{0,0,0,0};
    float4 xp = (l < Lx-1) ? *(const float4*)(x + (size_t)bl*Cc + c4 + Cc) : float4{0,0,0,0};
    float v0=0, v1=0, v2=0, v3=0;
    #pragma unroll
    for (int t = 0; t < Tt; ++t) {
        float w0 = cw[t*3+0], w1 = cw[t*3+1], w2 = cw[t*3+2];
        float inv = g[t] / sqrtf(var[t] + 1e-5f);
        float off = (cb[t] - mu[t]) * inv + be[t];
        float y0 = (w0*xm.x + w1*x0.x + w2*xp.x) * inv + off;
        float y1 = (w0*xm.y + w1*x0.y + w2*xp.y) * inv + off;
        float y2 = (w0*xm.z + w1*x0.z + w2*xp.z) * inv + off;
        float y3 = (w0*xm.w + w1*x0.w + w2*xp.w) * inv + off;
        v0 = v0 + (y0 - v0)*0.5f;  v1 = v1 + (y1 - v1)*0.5f;
        v2 = v2 + (y2 - v2)*0.5f;  v3 = v3 + (y3 - v3)*0.5f;
        float s0 = (v0 >= 1.0f) ? 1.0f : 0.0f;  float s1 = (v1 >= 1.0f) ? 1.0f : 0.0f;
        float s2 = (v2 >= 1.0f) ? 1.0f : 0.0f;  float s3 = (v3 >= 1.0f) ? 1.0f : 0.0f;
        uchar4 pk = { (uint8_t)s0, (uint8_t)s1, (uint8_t)s2, (uint8_t)s3 };
        *(uchar4*)(spk + (size_t)(bl*4 + t)*Cc + c4) = pk;
        v0 *= (1.0f - s0);  v1 *= (1.0f - s1);  v2 *= (1.0f - s2);  v3 *= (1.0f - s3);
    }
}

// ---------------- i8 3-pass GEMM, deep pipeline + LIF epilogue
// Tile 256x256, BK=64, 8 waves (2M x 4N), wave tile 128x64 (acc[8][4]=128 AGPR,
// proven no-spill at 2 waves/SIMD). 4 LDS bufs x (A 16KB + B 16KB) = 128 KB;
// prefetch depth 3; s_waitcnt vmcnt(8) per tile (never 0 in steady state);
// ONE barrier per tile; relaxed body {12 ds_reads, 4 sweeps, 32 MFMA+setprio}
// -- compiler inserts counted lgkm waits so MFMA overlaps the read/sweep stream.
// acc = (acc1*128 + acc2)*128 + acc3 exact in i32 (|acc| < 2^31).
template<int K, bool FINAL>
__global__ __launch_bounds__(512, 2)
void gemm_lif(const int8_t* __restrict__ A,
              const int8_t* __restrict__ Wq,      // [3 comps][HID][K]
              const float* __restrict__ invs,     // [1] 2^-s
              const float* __restrict__ bias,
              int8_t* __restrict__ spk_out, float* __restrict__ out_mean) {
    constexpr int KT  = K / 64;           // tiles per component pass
    constexpr int NKT = 3 * KT;           // three fixed-point component passes
    __shared__ int8_t lds[4 * 32768];     // 4 bufs x (A 16KB + B 16KB)

    const int tid  = threadIdx.x;
    const int lane = tid & 63;
    const int wid  = tid >> 6;
    const int wm   = wid >> 2;        // 0..1
    const int wn   = wid & 3;         // 0..3
    // XCD-chunked decode (1024 blocks): xcd = bid&7 owns 32 m-panels; within an
    // XCD, n varies fastest (4 n-blocks reuse one L2-resident A panel; B L2-resident).
    const int bid  = blockIdx.x;
    const int idx_ = bid >> 3;                     // 0..127
    const int n0   = (idx_ & 3) * 256;
    const int m0   = ((bid & 7) * 32 + (idx_ >> 2)) * 256;
    const int fr   = lane & 15;
    const int lq   = lane >> 4;
    const int swq  = (lq ^ ((fr >> 1) & 3)) * 16;   // conflict-free phys byte slot in 64B row
    const int srow = tid >> 2;                      // staging row (0..127)
    const int sl   = (tid & 3) ^ ((srow >> 1) & 3); // pre-swizzled source slot

    i32x4 acc[8][4] = {};

    // ---- stage one 64B-K tile (A 256rows + B 256rows) into buf: 4 gl16/thread
    auto stage = [&](int t, int8_t* buf) {
        const int8_t* Wc = Wq + (size_t)(t / KT) * HID * K;
        const int ko = (t % KT) * 64;
        gl16(A  + (size_t)(m0 +       srow) * K + ko + sl*16, buf +         tid*16);
        gl16(A  + (size_t)(m0 + 128 + srow) * K + ko + sl*16, buf +  8192 + tid*16);
        gl16(Wc + (size_t)(n0 +       srow) * K + ko + sl*16, buf + 16384 + tid*16);
        gl16(Wc + (size_t)(n0 + 128 + srow) * K + ko + sl*16, buf + 24576 + tid*16);
    };

    // ---- prologue: stage tiles 0,1,2 into bufs 0,1,2
    stage(0, &lds[0]);
    stage(1, &lds[32768]);
    stage(2, &lds[65536]);

    #pragma unroll 1
    for (int kt = 0; kt < NKT; ++kt) {
        if (kt == KT || kt == 2*KT) {     // component boundary: shift accumulated value
            #pragma unroll
            for (int i = 0; i < 8; ++i)
                #pragma unroll
                for (int j = 0; j < 4; ++j)
                    acc[i][j] *= 128;
        }
        if (kt < NKT-2)       asm volatile("s_waitcnt vmcnt(8)" ::: "memory");
        else if (kt == NKT-2) asm volatile("s_waitcnt vmcnt(4)" ::: "memory");
        else                  asm volatile("s_waitcnt vmcnt(0)" ::: "memory");
        blockbar();                       // tile kt landed for all waves

        const int cb = (kt & 3) * 32768;

        // ---- fragment reads (af first: first MFMA cluster's operands land first)
        i32x4 af[8], bf[4];
        #pragma unroll
        for (int i = 0; i < 8; ++i)
            af[i] = *(const i32x4*)&lds[cb + (wm*128 + i*16 + fr)*64 + swq];
        #pragma unroll
        for (int j = 0; j < 4; ++j)
            bf[j] = *(const i32x4*)&lds[cb + 16384 + (wn*64 + j*16 + fr)*64 + swq];

        // ---- staging sweeps for tile kt+3 (buffer (kt-1)&3: readers retired pre-barrier)
        if (kt + 3 < NKT) stage(kt + 3, &lds[((kt + 3) & 3) * 32768]);

        // ---- 32 MFMA; compiler inserts counted lgkm waits per cluster
        __builtin_amdgcn_s_setprio(1);
        #pragma unroll
        for (int i = 0; i < 8; ++i)
            #pragma unroll
            for (int j = 0; j < 4; ++j)
                acc[i][j] = __builtin_amdgcn_mfma_i32_16x16x64_i8(af[i], bf[j], acc[i][j], 0, 0, 0);
        __builtin_amdgcn_s_setprio(0);
    }

    // ---- epilogue: per-lane LIF over 4 acc regs (= 4 timesteps of one row)
    const float inv = invs[0];
    float bs[4];
    #pragma unroll
    for (int j = 0; j < 4; ++j)
        bs[j] = bias[n0 + wn*64 + j*16 + fr];
    const int rowq = lq * 4;
    #pragma unroll
    for (int i = 0; i < 8; ++i) {
        int rowLocal = m0 + wm*128 + i*16 + rowq;   // t=0 row; rows rowLocal..+3 = t 0..3
        int r = rowLocal >> 2;
        #pragma unroll
        for (int j = 0; j < 4; ++j) {
            int n = n0 + wn*64 + j*16 + fr;
            float v = 0.0f, ssum = 0.0f;
            #pragma unroll
            for (int t = 0; t < 4; ++t) {
                float xv = (float)acc[i][j][t] * inv + bs[j];
                v = v + (xv - v) * 0.5f;
                float s = (v >= 1.0f) ? 1.0f : 0.0f;
                if constexpr (FINAL) ssum += s;
                else spk_out[(size_t)(rowLocal + t) * HID + n] = (int8_t)s;
                v = v * (1.0f - s);
            }
            if constexpr (FINAL) out_mean[(size_t)r * HID + n] = ssum * 0.25f;
        }
    }
}

// ---------------- mean over L, two stages
__global__ void mean_partial(const float* __restrict__ out1, float* __restrict__ part) {
    int idx = blockIdx.x * blockDim.x + threadIdx.x;   // over 8*B*HID
    if (idx >= 8*Bb*HID) return;
    int seg = idx >> 15;
    int bd  = idx & (Bb*HID - 1);
    int b = bd >> 10, d = bd & (HID-1);
    const float* p = out1 + ((size_t)b*Lx + seg*64)*HID + d;
    float s = 0.0f;
    #pragma unroll 4
    for (int l = 0; l < 64; ++l) s += p[(size_t)l*HID];
    part[idx] = s;
}
__global__ void mean_final(const float* __restrict__ part, float* __restrict__ out2) {
    int idx = blockIdx.x * blockDim.x + threadIdx.x;   // B*HID
    if (idx >= Bb*HID) return;
    float s = 0.0f;
    #pragma unroll
    for (int k = 0; k < 8; ++k) s += part[k*Bb*HID + idx];
    out2[idx] = s * (1.0f / Lx);
}

extern "C" void kernel_launch(void* const* d_in, const int* in_sizes, int n_in,
                              void* d_out, int out_size, void* d_ws, size_t ws_size,
                              hipStream_t stream) {
    const float* x      = (const float*)d_in[0];
    const float* cw     = (const float*)d_in[1];
    const float* cb     = (const float*)d_in[2];
    const float* g      = (const float*)d_in[3];
    const float* be     = (const float*)d_in[4];
    const float* mu     = (const float*)d_in[5];
    const float* var    = (const float*)d_in[6];
    const float* enc_w  = (const float*)d_in[7];
    const float* enc_b  = (const float*)d_in[8];
    const float* cell_w = (const float*)d_in[9];
    const float* cell_b = (const float*)d_in[10];

    float* out1 = (float*)d_out;                    // [RR][HID]
    float* out2 = out1 + (size_t)RR * HID;          // [B][HID]

    // ---- ws layout (~136 MB; 144 MB proven available)
    uint8_t* ws = (uint8_t*)d_ws;
    int8_t* X = (int8_t*)ws;                               // 64 MB (spk1 16MB -> layer2 out)
    int8_t* Y = (int8_t*)(ws + (size_t)64*1024*1024);      // 64 MB (layer1 out)
    int8_t* qEnc = (int8_t*)(ws + (size_t)128*1024*1024);  // 3*HID*Cc
    int8_t* qC0  = qEnc + (size_t)3*HID*Cc;                // 3*HID*HID
    int8_t* qC1  = qC0  + (size_t)3*HID*HID;               // 3*HID*HID
    float*  amax = (float*)(qC1 + (size_t)3*HID*HID);
    float*  invv = amax + 4;
    float*  part = invv + 4;                               // 8*B*HID = 1 MB

    // ---- weight quantization (exact 21-bit fixed point, per-matrix pow2 scale)
    zero_f<<<1, 4, 0, stream>>>(amax, 3);
    absmax3<<<dim3(64, 3), 256, 0, stream>>>(enc_w, cell_w, amax);
    quant3<<<dim3((HID*HID + 255)/256, 3), 256, 0, stream>>>(enc_w, cell_w, amax,
                                                             qEnc, qC0, qC1, invv);

    // ---- conv + BN + LIF -> spk1 (= X[0:16MB])
    conv_bn_lif<<<(Bb*Lx*Cc/4 + 255)/256, 256, 0, stream>>>(x, cw, cb, g, be, mu, var, X);

    // ---- full-problem trunk, one dispatch per layer (1024 blocks, XCD-decoded)
    gemm_lif<Cc,  false><<<1024, 512, 0, stream>>>(X, qEnc, invv + 0, enc_b,      Y, nullptr);
    gemm_lif<HID, false><<<1024, 512, 0, stream>>>(Y, qC0,  invv + 1, cell_b,     X, nullptr);
    gemm_lif<HID, true ><<<1024, 512, 0, stream>>>(X, qC1,  invv + 2, cell_b+HID, nullptr, out1);

    // ---- means
    mean_partial<<<(8*Bb*HID + 255)/256, 256, 0, stream>>>(out1, part);
    mean_final<<<(Bb*HID + 255)/256, 256, 0, stream>>>(part, out2);
}

// Round 14
// 418.373 us; speedup vs baseline: 3.6241x; 1.0732x over previous
//
#include <hip/hip_runtime.h>
#include <hip/hip_bf16.h>
#include <stdint.h>

#define Bb 32
#define Lx 512
#define Cc 256
#define Tt 4
#define HID 1024
#define RR (Bb*Lx)          // 16384 logical rows (b*L+l)
#define MRf (RR*Tt)         // 65536 interleaved rows (r*4+t)

typedef int i32x4 __attribute__((ext_vector_type(4)));

// ---------------- async global->LDS, 16B per lane
__device__ __forceinline__ void gl16(const void* g, void* l) {
    __builtin_amdgcn_global_load_lds(
        (const __attribute__((address_space(1))) unsigned int*)g,
        (__attribute__((address_space(3))) unsigned int*)l, 16, 0, 0);
}
__device__ __forceinline__ void blockbar() {
    asm volatile("" ::: "memory");
    __builtin_amdgcn_s_barrier();
    asm volatile("" ::: "memory");
}

// ---------------- per-row weight quantization: w*2^s_row = i1*2^14 + i2*2^7 + i3
// One wave per output row (exact fixed point; per-row pow2 scale).
__global__ void quant_rows(const float* __restrict__ enc_w,
                           const float* __restrict__ cell_w,
                           int8_t* __restrict__ qEnc, int8_t* __restrict__ qC0,
                           int8_t* __restrict__ qC1, float* __restrict__ invN) {
    const int gw   = (blockIdx.x * blockDim.x + threadIdx.x) >> 6;  // 0..3071
    const int lane = threadIdx.x & 63;
    const int mat  = gw >> 10;           // 0 enc, 1 cell0, 2 cell1
    const int row  = gw & 1023;
    const int Kk   = (mat == 0) ? Cc : HID;
    const float* w = (mat == 0) ? enc_w + (size_t)row * Cc
                                : cell_w + (size_t)(mat-1)*HID*HID + (size_t)row * HID;
    int8_t* q = ((mat == 0) ? qEnc : (mat == 1 ? qC0 : qC1)) + (size_t)row * Kk;
    const size_t nElem = (size_t)HID * Kk;

    float m = 0.0f;
    for (int k = lane; k < Kk; k += 64) m = fmaxf(m, fabsf(w[k]));
    #pragma unroll
    for (int o = 32; o; o >>= 1) m = fmaxf(m, __shfl_xor(m, o));
    m = fmaxf(m, 1e-20f);
    float sp = exp2f(floorf(log2f(126.0f * 16384.0f / m)));
    if (m * sp > 126.0f * 16384.0f) sp *= 0.5f;     // guard log2 boundary
    if (lane == 0) invN[mat*HID + row] = 1.0f / sp;
    for (int k = lane; k < Kk; k += 64) {
        float v  = rintf(w[k] * sp);                // |v| <= 126*2^14, integer-exact in f32
        float i1 = rintf(v * (1.0f/16384.0f));      // |i1| <= 126
        float r1 = v - i1 * 16384.0f;               // |r1| <= 2^13, exact
        float i2 = rintf(r1 * (1.0f/128.0f));       // |i2| <= 64
        float r2 = r1 - i2 * 128.0f;                // |r2| <= 64, exact
        q[k]           = (int8_t)i1;
        q[nElem + k]   = (int8_t)i2;
        q[2*nElem + k] = (int8_t)r2;
    }
}

__global__ void zero_out(float* p, int n) {
    int i = blockIdx.x * 256 + threadIdx.x;
    if (i < n) p[i] = 0.0f;
}

// ---------------- Stage 1: conv(K=3 over L) + BN + LIF -> i8 spikes, rows r*4+t
__global__ void conv_bn_lif(const float* __restrict__ x,
                            const float* __restrict__ cw, const float* __restrict__ cb,
                            const float* __restrict__ g,  const float* __restrict__ be,
                            const float* __restrict__ mu, const float* __restrict__ var,
                            int8_t* __restrict__ spk) {   // [RR*4][Cc]
    int idx = blockIdx.x * blockDim.x + threadIdx.x;      // over B*L*C/4
    if (idx >= Bb*Lx*Cc/4) return;
    int bl = idx / (Cc/4);
    int c4 = (idx % (Cc/4)) * 4;
    int l  = bl % Lx;
    float4 x0 = *(const float4*)(x + (size_t)bl*Cc + c4);
    float4 xm = (l > 0)    ? *(const float4*)(x + (size_t)bl*Cc + c4 - Cc) : float4{0,0,0,0};
    float4 xp = (l < Lx-1) ? *(const float4*)(x + (size_t)bl*Cc + c4 + Cc) : float4{0,0,0,0};
    float v0=0, v1=0, v2=0, v3=0;
    #pragma unroll
    for (int t = 0; t < Tt; ++t) {
        float w0 = cw[t*3+0], w1 = cw[t*3+1], w2 = cw[t*3+2];
        float inv = g[t] / sqrtf(var[t] + 1e-5f);
        float off = (cb[t] - mu[t]) * inv + be[t];
        float y0 = (w0*xm.x + w1*x0.x + w2*xp.x) * inv + off;
        float y1 = (w0*xm.y + w1*x0.y + w2*xp.y) * inv + off;
        float y2 = (w0*xm.z + w1*x0.z + w2*xp.z) * inv + off;
        float y3 = (w0*xm.w + w1*x0.w + w2*xp.w) * inv + off;
        v0 = v0 + (y0 - v0)*0.5f;  v1 = v1 + (y1 - v1)*0.5f;
        v2 = v2 + (y2 - v2)*0.5f;  v3 = v3 + (y3 - v3)*0.5f;
        float s0 = (v0 >= 1.0f) ? 1.0f : 0.0f;  float s1 = (v1 >= 1.0f) ? 1.0f : 0.0f;
        float s2 = (v2 >= 1.0f) ? 1.0f : 0.0f;  float s3 = (v3 >= 1.0f) ? 1.0f : 0.0f;
        uchar4 pk = { (uint8_t)s0, (uint8_t)s1, (uint8_t)s2, (uint8_t)s3 };
        *(uchar4*)(spk + (size_t)(bl*4 + t)*Cc + c4) = pk;
        v0 *= (1.0f - s0);  v1 *= (1.0f - s1);  v2 *= (1.0f - s2);  v3 *= (1.0f - s3);
    }
}

// ---------------- i8 3-pass GEMM, deep pipeline + LIF epilogue (+ fused L-mean)
// Tile 256x256, BK=64, 8 waves (2M x 4N), wave tile 128x64 (acc[8][4]=128 AGPR).
// 4 LDS bufs x 32KB; prefetch 3; counted vmcnt(8) (never 0 steady); ONE barrier/tile.
// At the measured LDS roofline: matrix 1307 cyc/tile vs LDS ~1300-1450 -> util ~47%.
// acc = (acc1*128 + acc2)*128 + acc3 exact in i32 (|acc| < 2^31, per-row scale).
template<int K, bool FINAL>
__global__ __launch_bounds__(512, 2)
void gemm_lif(const int8_t* __restrict__ A,
              const int8_t* __restrict__ Wq,      // [3 comps][HID][K]
              const float* __restrict__ invN,     // [HID] per-row 2^-s
              const float* __restrict__ bias,
              int8_t* __restrict__ spk_out, float* __restrict__ out_mean,
              float* __restrict__ out_sum) {
    constexpr int KT  = K / 64;           // tiles per component pass
    constexpr int NKT = 3 * KT;           // three fixed-point component passes
    __shared__ int8_t lds[4 * 32768];     // 4 bufs x (A 16KB + B 16KB)

    const int tid  = threadIdx.x;
    const int lane = tid & 63;
    const int wid  = tid >> 6;
    const int wm   = wid >> 2;        // 0..1
    const int wn   = wid & 3;         // 0..3
    // XCD-chunked decode (1024 blocks): xcd = bid&7 owns 32 m-panels; within an
    // XCD, n varies fastest (4 n-blocks reuse one L2-resident A panel).
    const int bid  = blockIdx.x;
    const int idx_ = bid >> 3;                     // 0..127
    const int n0   = (idx_ & 3) * 256;
    const int m0   = ((bid & 7) * 32 + (idx_ >> 2)) * 256;
    const int fr   = lane & 15;
    const int lq   = lane >> 4;
    const int swq  = (lq ^ ((fr >> 1) & 3)) * 16;   // conflict-free phys byte slot in 64B row
    const int srow = tid >> 2;                      // staging row (0..127)
    const int sl   = (tid & 3) ^ ((srow >> 1) & 3); // pre-swizzled source slot

    i32x4 acc[8][4] = {};

    // ---- stage one 64B-K tile (A 256rows + B 256rows) into buf: 4 gl16/thread
    auto stage = [&](int t, int8_t* buf) {
        const int8_t* Wc = Wq + (size_t)(t / KT) * HID * K;
        const int ko = (t % KT) * 64;
        gl16(A  + (size_t)(m0 +       srow) * K + ko + sl*16, buf +         tid*16);
        gl16(A  + (size_t)(m0 + 128 + srow) * K + ko + sl*16, buf +  8192 + tid*16);
        gl16(Wc + (size_t)(n0 +       srow) * K + ko + sl*16, buf + 16384 + tid*16);
        gl16(Wc + (size_t)(n0 + 128 + srow) * K + ko + sl*16, buf + 24576 + tid*16);
    };

    // ---- prologue: stage tiles 0,1,2 into bufs 0,1,2
    stage(0, &lds[0]);
    stage(1, &lds[32768]);
    stage(2, &lds[65536]);

    #pragma unroll 1
    for (int kt = 0; kt < NKT; ++kt) {
        if (kt == KT || kt == 2*KT) {     // component boundary: shift accumulated value
            #pragma unroll
            for (int i = 0; i < 8; ++i)
                #pragma unroll
                for (int j = 0; j < 4; ++j)
                    acc[i][j] *= 128;
        }
        if (kt < NKT-2)       asm volatile("s_waitcnt vmcnt(8)" ::: "memory");
        else if (kt == NKT-2) asm volatile("s_waitcnt vmcnt(4)" ::: "memory");
        else                  asm volatile("s_waitcnt vmcnt(0)" ::: "memory");
        blockbar();                       // tile kt landed for all waves

        const int cb = (kt & 3) * 32768;

        // ---- fragment reads (af first: first MFMA cluster's operands land first)
        i32x4 af[8], bf[4];
        #pragma unroll
        for (int i = 0; i < 8; ++i)
            af[i] = *(const i32x4*)&lds[cb + (wm*128 + i*16 + fr)*64 + swq];
        #pragma unroll
        for (int j = 0; j < 4; ++j)
            bf[j] = *(const i32x4*)&lds[cb + 16384 + (wn*64 + j*16 + fr)*64 + swq];

        // ---- staging sweeps for tile kt+3 (buffer (kt-1)&3: readers retired pre-barrier)
        if (kt + 3 < NKT) stage(kt + 3, &lds[((kt + 3) & 3) * 32768]);

        // ---- 32 MFMA; compiler inserts counted lgkm waits per cluster
        __builtin_amdgcn_s_setprio(1);
        #pragma unroll
        for (int i = 0; i < 8; ++i)
            #pragma unroll
            for (int j = 0; j < 4; ++j)
                acc[i][j] = __builtin_amdgcn_mfma_i32_16x16x64_i8(af[i], bf[j], acc[i][j], 0, 0, 0);
        __builtin_amdgcn_s_setprio(0);
    }

    // ---- epilogue: per-lane LIF over 4 acc regs (= 4 timesteps of one row)
    float bs[4], iv[4], msum[4] = {0,0,0,0};
    #pragma unroll
    for (int j = 0; j < 4; ++j) {
        int n = n0 + wn*64 + j*16 + fr;
        bs[j] = bias[n];
        iv[j] = invN[n];
    }
    const int rowq = lq * 4;
    #pragma unroll
    for (int i = 0; i < 8; ++i) {
        int rowLocal = m0 + wm*128 + i*16 + rowq;   // t=0 row; rows rowLocal..+3 = t 0..3
        int r = rowLocal >> 2;
        #pragma unroll
        for (int j = 0; j < 4; ++j) {
            int n = n0 + wn*64 + j*16 + fr;
            float v = 0.0f, ssum = 0.0f;
            #pragma unroll
            for (int t = 0; t < 4; ++t) {
                float xv = (float)acc[i][j][t] * iv[j] + bs[j];
                v = v + (xv - v) * 0.5f;
                float s = (v >= 1.0f) ? 1.0f : 0.0f;
                if constexpr (FINAL) ssum += s;
                else spk_out[(size_t)(rowLocal + t) * HID + n] = (int8_t)s;
                v = v * (1.0f - s);
            }
            if constexpr (FINAL) {
                out_mean[(size_t)r * HID + n] = ssum * 0.25f;
                msum[j] += ssum;            // integer <= 4, exact
            }
        }
    }
    if constexpr (FINAL) {
        // fused mean over L: reduce msum over lq (shfl) -> one dyadic atomicAdd per (fr,j).
        // All partials are multiples of 2^-11 and < 2 -> exact f32, order-independent.
        const int b = m0 >> 11;             // all 64 r's of this block share b
        #pragma unroll
        for (int j = 0; j < 4; ++j) {
            float v = msum[j];
            v += __shfl_xor(v, 16);
            v += __shfl_xor(v, 32);
            if (lq == 0) {
                int n = n0 + wn*64 + j*16 + fr;
                atomicAdd(out_sum + (size_t)b * HID + n, v * (0.25f / 512.0f));
            }
        }
    }
}

extern "C" void kernel_launch(void* const* d_in, const int* in_sizes, int n_in,
                              void* d_out, int out_size, void* d_ws, size_t ws_size,
                              hipStream_t stream) {
    const float* x      = (const float*)d_in[0];
    const float* cw     = (const float*)d_in[1];
    const float* cb     = (const float*)d_in[2];
    const float* g      = (const float*)d_in[3];
    const float* be     = (const float*)d_in[4];
    const float* mu     = (const float*)d_in[5];
    const float* var    = (const float*)d_in[6];
    const float* enc_w  = (const float*)d_in[7];
    const float* enc_b  = (const float*)d_in[8];
    const float* cell_w = (const float*)d_in[9];
    const float* cell_b = (const float*)d_in[10];

    float* out1 = (float*)d_out;                    // [RR][HID]
    float* out2 = out1 + (size_t)RR * HID;          // [B][HID]

    // ---- ws layout (~135 MB; 144 MB proven available)
    uint8_t* ws = (uint8_t*)d_ws;
    int8_t* X = (int8_t*)ws;                               // 64 MB (spk1 16MB -> layer2 out)
    int8_t* Y = (int8_t*)(ws + (size_t)64*1024*1024);      // 64 MB (layer1 out)
    int8_t* qEnc = (int8_t*)(ws + (size_t)128*1024*1024);  // 3*HID*Cc
    int8_t* qC0  = qEnc + (size_t)3*HID*Cc;                // 3*HID*HID
    int8_t* qC1  = qC0  + (size_t)3*HID*HID;               // 3*HID*HID
    float*  invN = (float*)(qC1 + (size_t)3*HID*HID);      // [3*HID]

    // ---- per-row weight quantization (1 wave/row; 3072 rows; 768 blocks)
    quant_rows<<<768, 256, 0, stream>>>(enc_w, cell_w, qEnc, qC0, qC1, invN);

    // ---- conv + BN + LIF -> spk1 (= X[0:16MB]); zero out2 for the fused mean
    conv_bn_lif<<<(Bb*Lx*Cc/4 + 255)/256, 256, 0, stream>>>(x, cw, cb, g, be, mu, var, X);
    zero_out<<<(Bb*HID + 255)/256, 256, 0, stream>>>(out2, Bb*HID);

    // ---- full-problem trunk, one dispatch per layer (1024 blocks, XCD-decoded)
    gemm_lif<Cc,  false><<<1024, 512, 0, stream>>>(X, qEnc, invN,        enc_b,
                                                   Y, nullptr, nullptr);
    gemm_lif<HID, false><<<1024, 512, 0, stream>>>(Y, qC0,  invN + HID,  cell_b,
                                                   X, nullptr, nullptr);
    gemm_lif<HID, true ><<<1024, 512, 0, stream>>>(X, qC1,  invN + 2*HID, cell_b + HID,
                                                   nullptr, out1, out2);
}